// Round 1
// baseline (71.991 us; speedup 1.0000x reference)
//
#include <hip/hip_runtime.h>
#include <math.h>

#define HID 4096
#define NH 32
#define DK 128
#define DV 128
#define NQKV 12288              // NH*DK*2 + NH*DV
#define ROWS1 16448             // NQKV + HID + NH + NH

// d_out layout: [result 4096 | S 32*128*128=524288 | new_conv_state 12288*3=36864]
#define OUT_S_OFF 4096
#define OUT_CONV_OFF 528384

// ws layout (floats): [qkv 12288 | z 4096 | a 32 | b 32 | gated 4096]
#define WS_Z_OFF 12288
#define WS_A_OFF 16384
#define WS_B_OFF 16416
#define WS_G_OFF 16448

__device__ __forceinline__ float wave_reduce_sum(float x) {
#pragma unroll
  for (int off = 32; off > 0; off >>= 1) x += __shfl_xor(x, off, 64);
  return x;
}

// Kernel 1: fused matvec for W_qkv, W_z, W_a, W_b against hs. One wave per row.
__global__ __launch_bounds__(256) void k_matvec_in(
    const float* __restrict__ hs,
    const float* __restrict__ Wqkv, const float* __restrict__ Wz,
    const float* __restrict__ Wa, const float* __restrict__ Wb,
    float* __restrict__ ws) {
  const int wave = threadIdx.x >> 6, lane = threadIdx.x & 63;
  const int row = blockIdx.x * 4 + wave;
  const float* W;
  int r;
  if (row < NQKV) { W = Wqkv; r = row; }
  else if (row < NQKV + HID) { W = Wz; r = row - NQKV; }
  else if (row < NQKV + HID + NH) { W = Wa; r = row - (NQKV + HID); }
  else { W = Wb; r = row - (NQKV + HID + NH); }
  const float4* __restrict__ Wr = (const float4*)(W + (size_t)r * HID);
  const float4* __restrict__ h4 = (const float4*)hs;
  float acc = 0.f;
#pragma unroll
  for (int j = 0; j < 16; ++j) {
    const float4 w = Wr[lane + j * 64];
    const float4 h = h4[lane + j * 64];
    acc += w.x * h.x + w.y * h.y + w.z * h.z + w.w * h.w;
  }
  acc = wave_reduce_sum(acc);
  if (lane == 0) ws[row] = acc;
}

// Kernel 2: one block per head. conv+silu, q/k norm, delta-rule state update,
// RMS norm + z-gating. Writes S_new and new_conv_state to d_out, gated to ws.
__global__ __launch_bounds__(256) void k_head(
    const float* __restrict__ delta_state, const float* __restrict__ conv_state,
    const float* __restrict__ conv_w, const float* __restrict__ A_log,
    const float* __restrict__ dt_bias, const float* __restrict__ rms_w,
    float* __restrict__ ws, float* __restrict__ dout) {
  const int h = blockIdx.x, t = threadIdx.x;
  __shared__ float S[DV * DK];          // 64 KB
  __shared__ float qn[DK], kn[DK], va[DV], dl[DV], ov[DV];
  __shared__ float sc[4];
  __shared__ float s_eg, s_beta, s_kq;
  const float* __restrict__ qkv = ws;

  // --- conv + silu over this head's q,k,v rows (3*128 rows) ---
  for (int idx = t; idx < 3 * 128; idx += 256) {
    const int seg = idx >> 7, li = idx & 127;
    const int row = seg * 4096 + h * 128 + li;
    const float c0 = conv_state[row * 3 + 0];
    const float c1 = conv_state[row * 3 + 1];
    const float c2 = conv_state[row * 3 + 2];
    const float w0 = conv_w[row * 4 + 0], w1 = conv_w[row * 4 + 1];
    const float w2 = conv_w[row * 4 + 2], w3 = conv_w[row * 4 + 3];
    const float x = qkv[row];
    const float co = w0 * c0 + w1 * c1 + w2 * c2 + w3 * x;
    const float act = co / (1.f + expf(-co));   // silu
    dout[OUT_CONV_OFF + row * 3 + 0] = c1;
    dout[OUT_CONV_OFF + row * 3 + 1] = c2;
    dout[OUT_CONV_OFF + row * 3 + 2] = x;
    if (seg == 0) qn[li] = act;
    else if (seg == 1) kn[li] = act;
    else va[li] = act;
  }
  __syncthreads();

  // --- q/k L2-norm factors, k·q, gate scalars (wave 0) ---
  if (t < 64) {
    const float q0 = qn[t], q1 = qn[t + 64];
    const float k0 = kn[t], k1 = kn[t + 64];
    float sq = q0 * q0 + q1 * q1;
    float sk = k0 * k0 + k1 * k1;
    float dq = q0 * k0 + q1 * k1;
#pragma unroll
    for (int off = 32; off > 0; off >>= 1) {
      sq += __shfl_xor(sq, off, 64);
      sk += __shfl_xor(sk, off, 64);
      dq += __shfl_xor(dq, off, 64);
    }
    if (t == 0) {
      const float rq = rsqrtf(sq + 1e-6f) * 0.08838834764831845f; // *1/sqrt(DK)
      const float rk = rsqrtf(sk + 1e-6f);
      sc[0] = rq; sc[1] = rk;
      s_kq = dq * rq * rk;
      const float aa = ws[WS_A_OFF + h] + dt_bias[h];
      const float gate = -expf(A_log[h]) * log1pf(expf(aa));
      s_eg = expf(gate);
      const float bb = ws[WS_B_OFF + h];
      s_beta = 1.f / (1.f + expf(-bb));
    }
  }
  __syncthreads();
  if (t < 128) { qn[t] *= sc[0]; kn[t] *= sc[1]; }

  // --- stage S into LDS (coalesced float4) ---
  const float4* __restrict__ Sg = (const float4*)(delta_state + (size_t)h * (DV * DK));
  float4* Sl = (float4*)S;
#pragma unroll
  for (int j = 0; j < 16; ++j) Sl[j * 256 + t] = Sg[j * 256 + t];
  __syncthreads();

  // --- per-row dots: r1 = S[v,:]·kn, r2 = S[v,:]·qn (2 threads per row) ---
  const int v = t >> 1, half = t & 1;
  const float* Srow = S + v * 128 + half * 64;
  const float* kh = kn + half * 64;
  const float* qh = qn + half * 64;
  float r1 = 0.f, r2 = 0.f;
#pragma unroll
  for (int j = 0; j < 64; ++j) {
    const int jj = (j + t) & 63;     // rotate to avoid LDS bank conflicts
    const float s = Srow[jj];
    r1 += s * kh[jj];
    r2 += s * qh[jj];
  }
  r1 += __shfl_xor(r1, 1, 64);
  r2 += __shfl_xor(r2, 1, 64);
  const float eg = s_eg;
  const float dv_ = s_beta * (va[v] - eg * r1);   // delta[v]
  const float o = eg * r2 + dv_ * s_kq;           // out[v] = S_new[v,:]·q
  if (half == 0) { dl[v] = dv_; ov[v] = o; }
  __syncthreads();

  // --- write S_new = eg*S + delta ⊗ kn to d_out ---
  float4* So = (float4*)(dout + OUT_S_OFF + (size_t)h * (DV * DK));
#pragma unroll
  for (int j = 0; j < 16; ++j) {
    const int fi = j * 256 + t;
    const int vv = fi >> 5;            // 32 float4 per row
    const int kk = (fi & 31) << 2;
    const float4 s = Sl[fi];
    const float d = dl[vv];
    float4 rr;
    rr.x = eg * s.x + d * kn[kk + 0];
    rr.y = eg * s.y + d * kn[kk + 1];
    rr.z = eg * s.z + d * kn[kk + 2];
    rr.w = eg * s.w + d * kn[kk + 3];
    So[fi] = rr;
  }

  // --- RMS norm + silu(z) gating ---
  if (t < 64) {
    const float o0 = ov[t], o1 = ov[t + 64];
    float ss = o0 * o0 + o1 * o1;
#pragma unroll
    for (int off = 32; off > 0; off >>= 1) ss += __shfl_xor(ss, off, 64);
    if (t == 0) sc[3] = rsqrtf(ss * (1.f / 128.f) + 1e-6f);
  }
  __syncthreads();
  if (t < 128) {
    const float zv = ws[WS_Z_OFF + h * 128 + t];
    const float g = ov[t] * sc[3] * rms_w[t] * (zv / (1.f + expf(-zv)));
    ws[WS_G_OFF + h * 128 + t] = g;
  }
}

// Kernel 3: result = W_out @ gated. One wave per row.
__global__ __launch_bounds__(256) void k_matvec_out(
    const float* __restrict__ Wout, const float* __restrict__ ws,
    float* __restrict__ dout) {
  const int wave = threadIdx.x >> 6, lane = threadIdx.x & 63;
  const int row = blockIdx.x * 4 + wave;
  const float4* __restrict__ Wr = (const float4*)(Wout + (size_t)row * HID);
  const float4* __restrict__ g4 = (const float4*)(ws + WS_G_OFF);
  float acc = 0.f;
#pragma unroll
  for (int j = 0; j < 16; ++j) {
    const float4 w = Wr[lane + j * 64];
    const float4 g = g4[lane + j * 64];
    acc += w.x * g.x + w.y * g.y + w.z * g.z + w.w * g.w;
  }
  acc = wave_reduce_sum(acc);
  if (lane == 0) dout[row] = acc;
}

extern "C" void kernel_launch(void* const* d_in, const int* in_sizes, int n_in,
                              void* d_out, int out_size, void* d_ws, size_t ws_size,
                              hipStream_t stream) {
  const float* hs         = (const float*)d_in[0];
  const float* delta_state= (const float*)d_in[1];
  const float* conv_state = (const float*)d_in[2];
  const float* Wqkv       = (const float*)d_in[3];
  const float* Wz         = (const float*)d_in[4];
  const float* Wa         = (const float*)d_in[5];
  const float* Wb         = (const float*)d_in[6];
  const float* Wout       = (const float*)d_in[7];
  const float* conv_w     = (const float*)d_in[8];
  const float* A_log      = (const float*)d_in[9];
  const float* dt_bias    = (const float*)d_in[10];
  const float* rms_w      = (const float*)d_in[11];
  float* ws  = (float*)d_ws;
  float* out = (float*)d_out;

  k_matvec_in<<<ROWS1 / 4, 256, 0, stream>>>(hs, Wqkv, Wz, Wa, Wb, ws);
  k_head<<<NH, 256, 0, stream>>>(delta_state, conv_state, conv_w, A_log,
                                 dt_bias, rms_w, ws, out);
  k_matvec_out<<<HID / 4, 256, 0, stream>>>(Wout, ws, out);
}

// Round 3
// 65.406 us; speedup vs baseline: 1.1007x; 1.1007x over previous
//
#include <hip/hip_runtime.h>
#include <math.h>

#define HID 4096
#define NH 32
#define DK 128
#define DV 128
#define NQKV 12288              // NH*DK*2 + NH*DV
#define ROWS1 16448             // NQKV + HID + NH + NH

// d_out layout: [result 4096 | S 32*128*128=524288 | new_conv_state 12288*3=36864]
#define OUT_S_OFF 4096
#define OUT_CONV_OFF 528384

// ws layout (floats): [qkv 12288 | z 4096 | a 32 | b 32 | o 4096]
#define WS_Z_OFF 12288
#define WS_A_OFF 16384
#define WS_B_OFF 16416
#define WS_O_OFF 16448

typedef float f32x4 __attribute__((ext_vector_type(4)));

__device__ __forceinline__ float wave_reduce_sum(float x) {
#pragma unroll
  for (int off = 32; off > 0; off >>= 1) x += __shfl_xor(x, off, 64);
  return x;
}

__device__ __forceinline__ float silu_f(float x) {
  return x / (1.f + __expf(-x));
}

// Kernel 1: fused matvec for W_qkv, W_z, W_a, W_b against hs. One wave per row.
// Also emits new_conv_state for qkv rows (needs only raw qkv + old conv_state).
__global__ __launch_bounds__(256) void k_matvec_in(
    const float* __restrict__ hs,
    const float* __restrict__ Wqkv, const float* __restrict__ Wz,
    const float* __restrict__ Wa, const float* __restrict__ Wb,
    const float* __restrict__ conv_state,
    float* __restrict__ ws, float* __restrict__ dout) {
  const int wave = threadIdx.x >> 6, lane = threadIdx.x & 63;
  const int row = blockIdx.x * 4 + wave;
  const float* W;
  int r;
  if (row < NQKV) { W = Wqkv; r = row; }
  else if (row < NQKV + HID) { W = Wz; r = row - NQKV; }
  else if (row < NQKV + HID + NH) { W = Wa; r = row - (NQKV + HID); }
  else { W = Wb; r = row - (NQKV + HID + NH); }
  const f32x4* __restrict__ Wr = (const f32x4*)(W + (size_t)r * HID);
  const f32x4* __restrict__ h4 = (const f32x4*)hs;
  float acc = 0.f;
#pragma unroll
  for (int j = 0; j < 16; ++j) {
    const f32x4 w = __builtin_nontemporal_load(&Wr[lane + j * 64]);
    const f32x4 h = h4[lane + j * 64];
    acc += w.x * h.x + w.y * h.y + w.z * h.z + w.w * h.w;
  }
  acc = wave_reduce_sum(acc);
  if (lane == 0) {
    ws[row] = acc;
    if (row < NQKV) {
      dout[OUT_CONV_OFF + row * 3 + 0] = conv_state[row * 3 + 1];
      dout[OUT_CONV_OFF + row * 3 + 1] = conv_state[row * 3 + 2];
      dout[OUT_CONV_OFF + row * 3 + 2] = acc;
    }
  }
}

// Kernel 2: 1024 blocks; block b owns head h=b>>5 and v-rows vbase..vbase+3.
// Redundantly recomputes the head's conv+silu+norm scalars (L2-cached, cheap),
// then one wave per S-row: r1=S·kn, r2=S·qn, delta, S_new write, o -> ws.
__global__ __launch_bounds__(256) void k_state(
    const float* __restrict__ delta_state, const float* __restrict__ conv_state,
    const float* __restrict__ conv_w, const float* __restrict__ A_log,
    const float* __restrict__ dt_bias,
    float* __restrict__ ws, float* __restrict__ dout) {
  const int bid = blockIdx.x;
  const int h = bid >> 5;
  const int vbase = (bid & 31) * 4;
  const int t = threadIdx.x;
  __shared__ __align__(16) float qn[DK];
  __shared__ __align__(16) float kn[DK];
  __shared__ float va4[4];
  __shared__ float s_eg, s_beta, s_kq, s_rq, s_rk;

  // conv + silu for this head's q (t<128) and k (t>=128) rows
  {
    const int seg = t >> 7, li = t & 127;
    const int row = seg * 4096 + h * 128 + li;
    const float c0 = conv_state[row * 3 + 0];
    const float c1 = conv_state[row * 3 + 1];
    const float c2 = conv_state[row * 3 + 2];
    const float w0 = conv_w[row * 4 + 0], w1 = conv_w[row * 4 + 1];
    const float w2 = conv_w[row * 4 + 2], w3 = conv_w[row * 4 + 3];
    const float co = w0 * c0 + w1 * c1 + w2 * c2 + w3 * ws[row];
    const float act = silu_f(co);
    if (seg == 0) qn[li] = act; else kn[li] = act;
  }
  // conv + silu for this block's 4 v rows
  if (t < 4) {
    const int row = 2 * 4096 + h * 128 + vbase + t;
    const float c0 = conv_state[row * 3 + 0];
    const float c1 = conv_state[row * 3 + 1];
    const float c2 = conv_state[row * 3 + 2];
    const float w0 = conv_w[row * 4 + 0], w1 = conv_w[row * 4 + 1];
    const float w2 = conv_w[row * 4 + 2], w3 = conv_w[row * 4 + 3];
    va4[t] = silu_f(w0 * c0 + w1 * c1 + w2 * c2 + w3 * ws[row]);
  }
  if (t == 4) {
    const float aa = ws[WS_A_OFF + h] + dt_bias[h];
    s_eg = __expf(-__expf(A_log[h]) * log1pf(__expf(aa)));
    s_beta = 1.f / (1.f + __expf(-ws[WS_B_OFF + h]));
  }
  __syncthreads();

  // q/k norms + k·q (wave 0)
  if (t < 64) {
    const float q0 = qn[t], q1 = qn[t + 64];
    const float k0 = kn[t], k1 = kn[t + 64];
    float sq = q0 * q0 + q1 * q1;
    float sk = k0 * k0 + k1 * k1;
    float dq = q0 * k0 + q1 * k1;
#pragma unroll
    for (int off = 32; off > 0; off >>= 1) {
      sq += __shfl_xor(sq, off, 64);
      sk += __shfl_xor(sk, off, 64);
      dq += __shfl_xor(dq, off, 64);
    }
    if (t == 0) {
      const float rq = rsqrtf(sq + 1e-6f) * 0.08838834764831845f; // *1/sqrt(DK)
      const float rk = rsqrtf(sk + 1e-6f);
      s_rq = rq; s_rk = rk;
      s_kq = dq * rq * rk;
    }
  }
  __syncthreads();
  if (t < 128) { qn[t] *= s_rq; kn[t] *= s_rk; }
  __syncthreads();

  // one wave per S-row
  const int w = t >> 6, lane = t & 63;
  const int v = vbase + w;
  const size_t roff = ((size_t)h * DV + v) * DK;
  const float2 s2 = ((const float2*)(delta_state + roff))[lane];
  const float2 kk = ((const float2*)kn)[lane];
  const float2 qq = ((const float2*)qn)[lane];
  float r1 = s2.x * kk.x + s2.y * kk.y;
  float r2 = s2.x * qq.x + s2.y * qq.y;
#pragma unroll
  for (int off = 32; off > 0; off >>= 1) {
    r1 += __shfl_xor(r1, off, 64);
    r2 += __shfl_xor(r2, off, 64);
  }
  const float eg = s_eg;
  const float dv_ = s_beta * (va4[w] - eg * r1);   // delta[v]
  const float o = eg * r2 + dv_ * s_kq;            // S_new[v,:]·q
  float2 out2;
  out2.x = eg * s2.x + dv_ * kk.x;
  out2.y = eg * s2.y + dv_ * kk.y;
  ((float2*)(dout + OUT_S_OFF + roff))[lane] = out2;
  if (lane == 0) ws[WS_O_OFF + h * DV + v] = o;
}

// Kernel 3: per-block gating prologue (RMS + silu(z)) into LDS, then
// result = W_out @ gated, one wave per row.
__global__ __launch_bounds__(256) void k_matvec_out(
    const float* __restrict__ Wout, const float* __restrict__ rms_w,
    float* __restrict__ ws, float* __restrict__ dout) {
  __shared__ __align__(16) float g[HID];
  __shared__ float scale[NH];
  const int t = threadIdx.x;
#pragma unroll
  for (int j = 0; j < 16; ++j) g[j * 256 + t] = ws[WS_O_OFF + j * 256 + t];
  __syncthreads();
  if (t < 32) {
    float ssum = 0.f;
#pragma unroll 4
    for (int v = 0; v < 128; ++v) {
      const float o = g[t * 128 + ((v + t) & 127)];  // rotate: avoid 32-way bank conflict
      ssum += o * o;
    }
    scale[t] = rsqrtf(ssum * (1.f / 128.f) + 1e-6f);
  }
  __syncthreads();
#pragma unroll
  for (int j = 0; j < 16; ++j) {
    const int idx = j * 256 + t;
    const int hh = idx >> 7, vv = idx & 127;
    const float zv = ws[WS_Z_OFF + idx];
    g[idx] = g[idx] * scale[hh] * rms_w[vv] * silu_f(zv);
  }
  __syncthreads();

  const int wave = t >> 6, lane = t & 63;
  const int row = blockIdx.x * 4 + wave;
  const f32x4* __restrict__ Wr = (const f32x4*)(Wout + (size_t)row * HID);
  const f32x4* __restrict__ g4 = (const f32x4*)g;
  float acc = 0.f;
#pragma unroll
  for (int j = 0; j < 16; ++j) {
    const f32x4 w = __builtin_nontemporal_load(&Wr[lane + j * 64]);
    const f32x4 gg = g4[lane + j * 64];
    acc += w.x * gg.x + w.y * gg.y + w.z * gg.z + w.w * gg.w;
  }
  acc = wave_reduce_sum(acc);
  if (lane == 0) dout[row] = acc;
}

extern "C" void kernel_launch(void* const* d_in, const int* in_sizes, int n_in,
                              void* d_out, int out_size, void* d_ws, size_t ws_size,
                              hipStream_t stream) {
  const float* hs         = (const float*)d_in[0];
  const float* delta_state= (const float*)d_in[1];
  const float* conv_state = (const float*)d_in[2];
  const float* Wqkv       = (const float*)d_in[3];
  const float* Wz         = (const float*)d_in[4];
  const float* Wa         = (const float*)d_in[5];
  const float* Wb         = (const float*)d_in[6];
  const float* Wout       = (const float*)d_in[7];
  const float* conv_w     = (const float*)d_in[8];
  const float* A_log      = (const float*)d_in[9];
  const float* dt_bias    = (const float*)d_in[10];
  const float* rms_w      = (const float*)d_in[11];
  float* ws  = (float*)d_ws;
  float* out = (float*)d_out;

  k_matvec_in<<<ROWS1 / 4, 256, 0, stream>>>(hs, Wqkv, Wz, Wa, Wb, conv_state,
                                             ws, out);
  k_state<<<NH * 32, 256, 0, stream>>>(delta_state, conv_state, conv_w, A_log,
                                       dt_bias, ws, out);
  k_matvec_out<<<HID / 4, 256, 0, stream>>>(Wout, rms_w, ws, out);
}

// Round 4
// 64.409 us; speedup vs baseline: 1.1177x; 1.0155x over previous
//
#include <hip/hip_runtime.h>
#include <math.h>

#define HID 4096
#define NH 32
#define DK 128
#define DV 128
#define NQKV 12288              // NH*DK*2 + NH*DV
#define ROWS1 16448             // NQKV + HID + NH + NH

// d_out layout: [result 4096 | S 32*128*128=524288 | new_conv_state 12288*3=36864]
#define OUT_S_OFF 4096
#define OUT_CONV_OFF 528384

// ws layout (floats): [qkv 12288 | z 4096 | a 32 | b 32 | o 4096]
#define WS_Z_OFF 12288
#define WS_A_OFF 16384
#define WS_B_OFF 16416
#define WS_O_OFF 16448

typedef float f32x4 __attribute__((ext_vector_type(4)));
typedef float f32x2 __attribute__((ext_vector_type(2)));

__device__ __forceinline__ float wave_reduce_sum(float x) {
#pragma unroll
  for (int off = 32; off > 0; off >>= 1) x += __shfl_xor(x, off, 64);
  return x;
}

__device__ __forceinline__ float silu_f(float x) {
  return x / (1.f + __expf(-x));
}

// Kernel 1: fused matvec for W_qkv, W_z, W_a, W_b against hs. One wave per row.
// hs staged in LDS (halves vmem issue count vs global re-reads).
// Also emits new_conv_state for qkv rows.
__global__ __launch_bounds__(256) void k_matvec_in(
    const float* __restrict__ hs,
    const float* __restrict__ Wqkv, const float* __restrict__ Wz,
    const float* __restrict__ Wa, const float* __restrict__ Wb,
    const float* __restrict__ conv_state,
    float* __restrict__ ws, float* __restrict__ dout) {
  __shared__ __align__(16) float hls[HID];
  {
    f32x4* hl4 = (f32x4*)hls;
    const f32x4* h4 = (const f32x4*)hs;
#pragma unroll
    for (int m = 0; m < 4; ++m)
      hl4[m * 256 + threadIdx.x] = h4[m * 256 + threadIdx.x];
  }
  __syncthreads();

  const int wave = threadIdx.x >> 6, lane = threadIdx.x & 63;
  const int row = blockIdx.x * 4 + wave;
  const float* W;
  int r;
  if (row < NQKV) { W = Wqkv; r = row; }
  else if (row < NQKV + HID) { W = Wz; r = row - NQKV; }
  else if (row < NQKV + HID + NH) { W = Wa; r = row - (NQKV + HID); }
  else { W = Wb; r = row - (NQKV + HID + NH); }
  const f32x4* __restrict__ Wr = (const f32x4*)(W + (size_t)r * HID);
  const f32x4* __restrict__ hl4 = (const f32x4*)hls;
  float acc0 = 0.f, acc1 = 0.f;
#pragma unroll
  for (int j = 0; j < 16; j += 2) {
    const f32x4 w0 = __builtin_nontemporal_load(&Wr[lane + j * 64]);
    const f32x4 h0 = hl4[lane + j * 64];
    const f32x4 w1 = __builtin_nontemporal_load(&Wr[lane + (j + 1) * 64]);
    const f32x4 h1 = hl4[lane + (j + 1) * 64];
    acc0 += w0.x * h0.x + w0.y * h0.y + w0.z * h0.z + w0.w * h0.w;
    acc1 += w1.x * h1.x + w1.y * h1.y + w1.z * h1.z + w1.w * h1.w;
  }
  float acc = wave_reduce_sum(acc0 + acc1);
  if (lane == 0) {
    ws[row] = acc;
    if (row < NQKV) {
      dout[OUT_CONV_OFF + row * 3 + 0] = conv_state[row * 3 + 1];
      dout[OUT_CONV_OFF + row * 3 + 1] = conv_state[row * 3 + 2];
      dout[OUT_CONV_OFF + row * 3 + 2] = acc;
    }
  }
}

// Kernel 2: 1024 blocks; block b owns head h=b>>5 and v-rows vbase..vbase+3.
// Redundantly recomputes the head's conv+silu+norm scalars (L2-cached, cheap),
// then one wave per S-row: r1=S·kn, r2=S·qn, delta, S_new write, o -> ws.
__global__ __launch_bounds__(256) void k_state(
    const float* __restrict__ delta_state, const float* __restrict__ conv_state,
    const float* __restrict__ conv_w, const float* __restrict__ A_log,
    const float* __restrict__ dt_bias,
    float* __restrict__ ws, float* __restrict__ dout) {
  const int bid = blockIdx.x;
  const int h = bid >> 5;
  const int vbase = (bid & 31) * 4;
  const int t = threadIdx.x;
  __shared__ __align__(16) float qn[DK];
  __shared__ __align__(16) float kn[DK];
  __shared__ float va4[4];
  __shared__ float s_eg, s_beta, s_kq, s_rq, s_rk;

  // conv + silu for this head's q (t<128) and k (t>=128) rows
  {
    const int seg = t >> 7, li = t & 127;
    const int row = seg * 4096 + h * 128 + li;
    const float c0 = conv_state[row * 3 + 0];
    const float c1 = conv_state[row * 3 + 1];
    const float c2 = conv_state[row * 3 + 2];
    const float w0 = conv_w[row * 4 + 0], w1 = conv_w[row * 4 + 1];
    const float w2 = conv_w[row * 4 + 2], w3 = conv_w[row * 4 + 3];
    const float co = w0 * c0 + w1 * c1 + w2 * c2 + w3 * ws[row];
    const float act = silu_f(co);
    if (seg == 0) qn[li] = act; else kn[li] = act;
  }
  // conv + silu for this block's 4 v rows
  if (t < 4) {
    const int row = 2 * 4096 + h * 128 + vbase + t;
    const float c0 = conv_state[row * 3 + 0];
    const float c1 = conv_state[row * 3 + 1];
    const float c2 = conv_state[row * 3 + 2];
    const float w0 = conv_w[row * 4 + 0], w1 = conv_w[row * 4 + 1];
    const float w2 = conv_w[row * 4 + 2], w3 = conv_w[row * 4 + 3];
    va4[t] = silu_f(w0 * c0 + w1 * c1 + w2 * c2 + w3 * ws[row]);
  }
  if (t == 4) {
    const float aa = ws[WS_A_OFF + h] + dt_bias[h];
    s_eg = __expf(-__expf(A_log[h]) * log1pf(__expf(aa)));
    s_beta = 1.f / (1.f + __expf(-ws[WS_B_OFF + h]));
  }
  __syncthreads();

  // q/k norms + k·q (wave 0)
  if (t < 64) {
    const float q0 = qn[t], q1 = qn[t + 64];
    const float k0 = kn[t], k1 = kn[t + 64];
    float sq = q0 * q0 + q1 * q1;
    float sk = k0 * k0 + k1 * k1;
    float dq = q0 * k0 + q1 * k1;
#pragma unroll
    for (int off = 32; off > 0; off >>= 1) {
      sq += __shfl_xor(sq, off, 64);
      sk += __shfl_xor(sk, off, 64);
      dq += __shfl_xor(dq, off, 64);
    }
    if (t == 0) {
      const float rq = rsqrtf(sq + 1e-6f) * 0.08838834764831845f; // *1/sqrt(DK)
      const float rk = rsqrtf(sk + 1e-6f);
      s_rq = rq; s_rk = rk;
      s_kq = dq * rq * rk;
    }
  }
  __syncthreads();
  if (t < 128) { qn[t] *= s_rq; kn[t] *= s_rk; }
  __syncthreads();

  // one wave per S-row
  const int w = t >> 6, lane = t & 63;
  const int v = vbase + w;
  const size_t roff = ((size_t)h * DV + v) * DK;
  const f32x2 s2 = __builtin_nontemporal_load(&((const f32x2*)(delta_state + roff))[lane]);
  const f32x2 kk = ((const f32x2*)kn)[lane];
  const f32x2 qq = ((const f32x2*)qn)[lane];
  float r1 = s2.x * kk.x + s2.y * kk.y;
  float r2 = s2.x * qq.x + s2.y * qq.y;
#pragma unroll
  for (int off = 32; off > 0; off >>= 1) {
    r1 += __shfl_xor(r1, off, 64);
    r2 += __shfl_xor(r2, off, 64);
  }
  const float eg = s_eg;
  const float dv_ = s_beta * (va4[w] - eg * r1);   // delta[v]
  const float o = eg * r2 + dv_ * s_kq;            // S_new[v,:]·q
  f32x2 out2;
  out2.x = eg * s2.x + dv_ * kk.x;
  out2.y = eg * s2.y + dv_ * kk.y;
  __builtin_nontemporal_store(out2, &((f32x2*)(dout + OUT_S_OFF + roff))[lane]);
  if (lane == 0) ws[WS_O_OFF + h * DV + v] = o;
}

// Kernel 3: slim gating prologue (parallel scale, f32x4 global->LDS), then
// result = W_out @ gated, one wave per row.
__global__ __launch_bounds__(256) void k_matvec_out(
    const float* __restrict__ Wout, const float* __restrict__ rms_w,
    float* __restrict__ ws, float* __restrict__ dout) {
  __shared__ __align__(16) float g[HID];
  __shared__ float scale[NH];
  const int t = threadIdx.x;
  // rms scale: 8 threads per head, shuffle-tree reduce within 8-lane groups
  {
    const int hh = t >> 3, sub = t & 7;
    const f32x4* o4 = (const f32x4*)(ws + WS_O_OFF + hh * 128 + sub * 16);
    float ss = 0.f;
#pragma unroll
    for (int j = 0; j < 4; ++j) {
      const f32x4 o = o4[j];
      ss += o.x * o.x + o.y * o.y + o.z * o.z + o.w * o.w;
    }
    ss += __shfl_xor(ss, 1, 64);
    ss += __shfl_xor(ss, 2, 64);
    ss += __shfl_xor(ss, 4, 64);
    if (sub == 0) scale[hh] = rsqrtf(ss * (1.f / 128.f) + 1e-6f);
  }
  __syncthreads();
  // gating: global -> LDS, f32x4
  {
    const f32x4* o4 = (const f32x4*)(ws + WS_O_OFF);
    const f32x4* z4 = (const f32x4*)(ws + WS_Z_OFF);
    const f32x4* r4 = (const f32x4*)rms_w;
    f32x4* g4 = (f32x4*)g;
#pragma unroll
    for (int j = 0; j < 4; ++j) {
      const int i = j * 256 + t;              // f32x4 index over 1024
      const f32x4 o = o4[i], z = z4[i], r = r4[i & 31];
      const float sc = scale[i >> 5];
      f32x4 gg;
      gg.x = o.x * sc * r.x * silu_f(z.x);
      gg.y = o.y * sc * r.y * silu_f(z.y);
      gg.z = o.z * sc * r.z * silu_f(z.z);
      gg.w = o.w * sc * r.w * silu_f(z.w);
      g4[i] = gg;
    }
  }
  __syncthreads();

  const int wave = t >> 6, lane = t & 63;
  const int row = blockIdx.x * 4 + wave;
  const f32x4* __restrict__ Wr = (const f32x4*)(Wout + (size_t)row * HID);
  const f32x4* __restrict__ g4 = (const f32x4*)g;
  float acc0 = 0.f, acc1 = 0.f;
#pragma unroll
  for (int j = 0; j < 16; j += 2) {
    const f32x4 w0 = __builtin_nontemporal_load(&Wr[lane + j * 64]);
    const f32x4 gg0 = g4[lane + j * 64];
    const f32x4 w1 = __builtin_nontemporal_load(&Wr[lane + (j + 1) * 64]);
    const f32x4 gg1 = g4[lane + (j + 1) * 64];
    acc0 += w0.x * gg0.x + w0.y * gg0.y + w0.z * gg0.z + w0.w * gg0.w;
    acc1 += w1.x * gg1.x + w1.y * gg1.y + w1.z * gg1.z + w1.w * gg1.w;
  }
  const float acc = wave_reduce_sum(acc0 + acc1);
  if (lane == 0) dout[row] = acc;
}

extern "C" void kernel_launch(void* const* d_in, const int* in_sizes, int n_in,
                              void* d_out, int out_size, void* d_ws, size_t ws_size,
                              hipStream_t stream) {
  const float* hs         = (const float*)d_in[0];
  const float* delta_state= (const float*)d_in[1];
  const float* conv_state = (const float*)d_in[2];
  const float* Wqkv       = (const float*)d_in[3];
  const float* Wz         = (const float*)d_in[4];
  const float* Wa         = (const float*)d_in[5];
  const float* Wb         = (const float*)d_in[6];
  const float* Wout       = (const float*)d_in[7];
  const float* conv_w     = (const float*)d_in[8];
  const float* A_log      = (const float*)d_in[9];
  const float* dt_bias    = (const float*)d_in[10];
  const float* rms_w      = (const float*)d_in[11];
  float* ws  = (float*)d_ws;
  float* out = (float*)d_out;

  k_matvec_in<<<ROWS1 / 4, 256, 0, stream>>>(hs, Wqkv, Wz, Wa, Wb, conv_state,
                                             ws, out);
  k_state<<<NH * 32, 256, 0, stream>>>(delta_state, conv_state, conv_w, A_log,
                                       dt_bias, ws, out);
  k_matvec_out<<<HID / 4, 256, 0, stream>>>(Wout, rms_w, ws, out);
}